// Round 1
// baseline (114.558 us; speedup 1.0000x reference)
//
#include <hip/hip_runtime.h>
#include <math.h>

#define B_ 8

__global__ __launch_bounds__(256) void init_ws_kernel(unsigned int* ws, int n) {
    int i = blockIdx.x * 256 + threadIdx.x;
    if (i < n) ws[i] = 0x7F800000u;  // +inf
}

// Fused both chamfer directions. blockIdx.z in [0, 2*B_):
//   z <  B_ : dir0, query = tar (per-target min over src)  -> "complete"
//   z >= B_ : dir1, query = src (per-source min over tar)  -> "accuracy"
// Each block: 256 threads x QPT queries in registers, one CHUNK-point tile of
// the "points" set staged in LDS (float4-padded, broadcast ds_read_b128).
// Partial mins combined across chunk-blocks via uint atomicMin (valid since
// all squared distances are >= 0, so uint order == float order).
template <int QPT, int CHUNK>
__global__ __launch_bounds__(256) void minsq_kernel(
    const float* __restrict__ tar, const float* __restrict__ src,
    unsigned int* __restrict__ ws, int N, int M)
{
    const int z   = blockIdx.z;
    const int dir = (z >= B_) ? 1 : 0;
    const int b   = dir ? (z - B_) : z;
    const float* __restrict__ qry = dir ? src : tar;
    const float* __restrict__ pts = dir ? tar : src;
    const int K = dir ? M : N;   // number of query points
    const int L = dir ? N : M;   // number of reference points
    unsigned int* __restrict__ out =
        ws + (dir ? (size_t)B_ * N : (size_t)0) + (size_t)b * K;

    const int base = blockIdx.y * CHUNK;     // point-tile offset
    if (base >= L) return;                   // block-uniform early exit
    const int cnt = min(CHUNK, L - base);

    __shared__ float4 sp[CHUNK];
    float* spf = (float*)sp;
    const float* __restrict__ psrc = pts + ((size_t)b * L + base) * 3;
    const int t = threadIdx.x;
    for (int i = t; i < cnt * 3; i += 256) {
        spf[(i / 3) * 4 + (i % 3)] = psrc[i];
    }
    __syncthreads();

    const int qbase = blockIdx.x * (256 * QPT);
    float qx[QPT], qy[QPT], qz[QPT], mn[QPT];
#pragma unroll
    for (int k = 0; k < QPT; ++k) {
        int qi = qbase + k * 256 + t;
        if (qi < K) {
            const float* qp = qry + ((size_t)b * K + qi) * 3;
            qx[k] = qp[0]; qy[k] = qp[1]; qz[k] = qp[2];
        } else {
            qx[k] = 0.f; qy[k] = 0.f; qz[k] = 0.f;
        }
        mn[k] = 3.4e38f;
    }

    if (cnt == CHUNK) {
#pragma unroll 4
        for (int j = 0; j < CHUNK; ++j) {
            float4 p = sp[j];
#pragma unroll
            for (int k = 0; k < QPT; ++k) {
                float dx = qx[k] - p.x;
                float dy = qy[k] - p.y;
                float dz = qz[k] - p.z;
                float d2 = fmaf(dx, dx, fmaf(dy, dy, dz * dz));
                mn[k] = fminf(mn[k], d2);
            }
        }
    } else {
        for (int j = 0; j < cnt; ++j) {
            float4 p = sp[j];
#pragma unroll
            for (int k = 0; k < QPT; ++k) {
                float dx = qx[k] - p.x;
                float dy = qy[k] - p.y;
                float dz = qz[k] - p.z;
                float d2 = fmaf(dx, dx, fmaf(dy, dy, dz * dz));
                mn[k] = fminf(mn[k], d2);
            }
        }
    }

#pragma unroll
    for (int k = 0; k < QPT; ++k) {
        int qi = qbase + k * 256 + t;
        if (qi < K) atomicMin(&out[qi], __float_as_uint(mn[k]));
    }
}

// Single-block final reduce: sqrt the per-point min squared distances, mean
// per direction, write (accuracy, complete, chamfer) in reference order.
__global__ __launch_bounds__(1024) void reduce_kernel(
    const unsigned int* __restrict__ ws, float* __restrict__ outp, int N, int M)
{
    const int t  = threadIdx.x;
    const int nt = B_ * N;   // dir0 region: per-target mins -> complete
    const int ns = B_ * M;   // dir1 region: per-source mins -> accuracy
    float s_t = 0.f, s_s = 0.f;
    for (int i = t; i < nt; i += 1024) s_t += sqrtf(__uint_as_float(ws[i]));
    for (int i = t; i < ns; i += 1024) s_s += sqrtf(__uint_as_float(ws[nt + i]));

#pragma unroll
    for (int off = 32; off > 0; off >>= 1) {
        s_t += __shfl_down(s_t, off);
        s_s += __shfl_down(s_s, off);
    }

    __shared__ float red_t[16], red_s[16];
    const int wid = t >> 6, lid = t & 63;
    if (lid == 0) { red_t[wid] = s_t; red_s[wid] = s_s; }
    __syncthreads();
    if (t == 0) {
        float ct = 0.f, ac = 0.f;
#pragma unroll
        for (int w = 0; w < 16; ++w) { ct += red_t[w]; ac += red_s[w]; }
        float complete = ct / (float)nt;
        float accuracy = ac / (float)ns;
        outp[0] = accuracy;
        outp[1] = complete;
        outp[2] = 0.5f * (accuracy + complete);
    }
}

extern "C" void kernel_launch(void* const* d_in, const int* in_sizes, int n_in,
                              void* d_out, int out_size, void* d_ws, size_t ws_size,
                              hipStream_t stream) {
    const float* tar = (const float*)d_in[0];
    const float* src = (const float*)d_in[1];
    const int N = in_sizes[0] / (B_ * 3);
    const int M = in_sizes[1] / (B_ * 3);
    unsigned int* ws = (unsigned int*)d_ws;

    const int tot = B_ * (N + M);
    init_ws_kernel<<<dim3((tot + 255) / 256), dim3(256), 0, stream>>>(ws, tot);

    constexpr int QPT = 4, CHUNK = 256;
    const int KL = (N > M) ? N : M;
    const int gx = (KL + 256 * QPT - 1) / (256 * QPT);
    const int gy = (KL + CHUNK - 1) / CHUNK;
    dim3 grid(gx, gy, 2 * B_);
    minsq_kernel<QPT, CHUNK><<<grid, dim3(256), 0, stream>>>(tar, src, ws, N, M);

    reduce_kernel<<<1, dim3(1024), 0, stream>>>(ws, (float*)d_out, N, M);
}

// Round 2
// 102.299 us; speedup vs baseline: 1.1198x; 1.1198x over previous
//
#include <hip/hip_runtime.h>
#include <math.h>

#define B_ 8

__global__ __launch_bounds__(256) void init_ws_kernel(unsigned int* ws, int n) {
    int i = blockIdx.x * 256 + threadIdx.x;
    if (i < n) ws[i] = 0x7F800000u;  // +inf
}

// Fused both chamfer directions. blockIdx.z in [0, 2*B_):
//   z <  B_ : dir0, query = tar (per-target min over src)  -> "complete"
//   z >= B_ : dir1, query = src (per-source min over tar)  -> "accuracy"
// d^2 = |q|^2 + |p|^2 - 2 q.p  -> inner loop = 3 FMA + 1 min per pair.
// LDS tile stores {px,py,pz,|p|^2}; registers hold -2q per query; |q|^2 is
// added once after the min (monotone shift). Cross-block min combine via
// uint atomicMin (d^2 clamped >= 0, so uint order == float order).
template <int QPT, int CHUNK>
__global__ __launch_bounds__(256) void minsq_kernel(
    const float* __restrict__ tar, const float* __restrict__ src,
    unsigned int* __restrict__ ws, int N, int M)
{
    const int z   = blockIdx.z;
    const int dir = (z >= B_) ? 1 : 0;
    const int b   = dir ? (z - B_) : z;
    const float* __restrict__ qry = dir ? src : tar;
    const float* __restrict__ pts = dir ? tar : src;
    const int K = dir ? M : N;   // number of query points
    const int L = dir ? N : M;   // number of reference points
    unsigned int* __restrict__ out =
        ws + (dir ? (size_t)B_ * N : (size_t)0) + (size_t)b * K;

    const int base = blockIdx.y * CHUNK;     // point-tile offset
    if (base >= L) return;                   // block-uniform early exit
    const int cnt = min(CHUNK, L - base);

    __shared__ float4 sp[CHUNK];
    const float* __restrict__ psrc = pts + ((size_t)b * L + base) * 3;
    const int t = threadIdx.x;
    for (int i = t; i < cnt; i += 256) {
        float px = psrc[3 * i + 0];
        float py = psrc[3 * i + 1];
        float pz = psrc[3 * i + 2];
        float pw = fmaf(px, px, fmaf(py, py, pz * pz));
        sp[i] = make_float4(px, py, pz, pw);
    }
    __syncthreads();

    const int qbase = blockIdx.x * (256 * QPT);
    float qx2[QPT], qy2[QPT], qz2[QPT], qw[QPT], mn[QPT];
#pragma unroll
    for (int k = 0; k < QPT; ++k) {
        int qi = qbase + k * 256 + t;
        if (qi < K) {
            const float* qp = qry + ((size_t)b * K + qi) * 3;
            float x = qp[0], y = qp[1], zc = qp[2];
            qx2[k] = -2.f * x; qy2[k] = -2.f * y; qz2[k] = -2.f * zc;
            qw[k] = fmaf(x, x, fmaf(y, y, zc * zc));
        } else {
            qx2[k] = 0.f; qy2[k] = 0.f; qz2[k] = 0.f; qw[k] = 0.f;
        }
        mn[k] = 3.4e38f;
    }

    if (cnt == CHUNK) {
#pragma unroll 4
        for (int j = 0; j < CHUNK; ++j) {
            float4 p = sp[j];
#pragma unroll
            for (int k = 0; k < QPT; ++k) {
                float d2 = fmaf(qx2[k], p.x,
                           fmaf(qy2[k], p.y,
                           fmaf(qz2[k], p.z, p.w)));
                mn[k] = fminf(mn[k], d2);
            }
        }
    } else {
        for (int j = 0; j < cnt; ++j) {
            float4 p = sp[j];
#pragma unroll
            for (int k = 0; k < QPT; ++k) {
                float d2 = fmaf(qx2[k], p.x,
                           fmaf(qy2[k], p.y,
                           fmaf(qz2[k], p.z, p.w)));
                mn[k] = fminf(mn[k], d2);
            }
        }
    }

#pragma unroll
    for (int k = 0; k < QPT; ++k) {
        int qi = qbase + k * 256 + t;
        if (qi < K) {
            float d2 = fmaxf(mn[k] + qw[k], 0.f);   // clamp roundoff negatives
            atomicMin(&out[qi], __float_as_uint(d2));
        }
    }
}

// Single-block final reduce: sqrt the per-point min squared distances, mean
// per direction, write (accuracy, complete, chamfer) in reference order.
__global__ __launch_bounds__(1024) void reduce_kernel(
    const unsigned int* __restrict__ ws, float* __restrict__ outp, int N, int M)
{
    const int t  = threadIdx.x;
    const int nt = B_ * N;   // dir0 region: per-target mins -> complete
    const int ns = B_ * M;   // dir1 region: per-source mins -> accuracy
    float s_t = 0.f, s_s = 0.f;
    for (int i = t; i < nt; i += 1024) s_t += sqrtf(__uint_as_float(ws[i]));
    for (int i = t; i < ns; i += 1024) s_s += sqrtf(__uint_as_float(ws[nt + i]));

#pragma unroll
    for (int off = 32; off > 0; off >>= 1) {
        s_t += __shfl_down(s_t, off);
        s_s += __shfl_down(s_s, off);
    }

    __shared__ float red_t[16], red_s[16];
    const int wid = t >> 6, lid = t & 63;
    if (lid == 0) { red_t[wid] = s_t; red_s[wid] = s_s; }
    __syncthreads();
    if (t == 0) {
        float ct = 0.f, ac = 0.f;
#pragma unroll
        for (int w = 0; w < 16; ++w) { ct += red_t[w]; ac += red_s[w]; }
        float complete = ct / (float)nt;
        float accuracy = ac / (float)ns;
        outp[0] = accuracy;
        outp[1] = complete;
        outp[2] = 0.5f * (accuracy + complete);
    }
}

extern "C" void kernel_launch(void* const* d_in, const int* in_sizes, int n_in,
                              void* d_out, int out_size, void* d_ws, size_t ws_size,
                              hipStream_t stream) {
    const float* tar = (const float*)d_in[0];
    const float* src = (const float*)d_in[1];
    const int N = in_sizes[0] / (B_ * 3);
    const int M = in_sizes[1] / (B_ * 3);
    unsigned int* ws = (unsigned int*)d_ws;

    const int tot = B_ * (N + M);
    init_ws_kernel<<<dim3((tot + 255) / 256), dim3(256), 0, stream>>>(ws, tot);

    constexpr int QPT = 8, CHUNK = 256;
    const int KL = (N > M) ? N : M;
    const int gx = (KL + 256 * QPT - 1) / (256 * QPT);
    const int gy = (KL + CHUNK - 1) / CHUNK;
    dim3 grid(gx, gy, 2 * B_);
    minsq_kernel<QPT, CHUNK><<<grid, dim3(256), 0, stream>>>(tar, src, ws, N, M);

    reduce_kernel<<<1, dim3(1024), 0, stream>>>(ws, (float*)d_out, N, M);
}

// Round 3
// 85.498 us; speedup vs baseline: 1.3399x; 1.1965x over previous
//
#include <hip/hip_runtime.h>
#include <math.h>

#define B_ 8

// ws layout (uint/float words):
//   [0,          B_*N)        dir0 per-target min d^2 (uint-ordered floats)
//   [B_*N,       B_*(N+M))    dir1 per-source min d^2
//   [S2,         S2+128)      reduce partial sums, dir0 (float)
//   [S2+128,     S2+256)      reduce partial sums, dir1 (float)

__global__ __launch_bounds__(256) void init_ws_kernel(unsigned int* ws, int n) {
    int i = blockIdx.x * 256 + threadIdx.x;
    if (i < n) ws[i] = 0x7F800000u;  // +inf
}

// Fused both chamfer directions. blockIdx.z in [0, 2*B_):
//   z <  B_ : query = tar, min over src  -> "complete"
//   z >= B_ : query = src, min over tar  -> "accuracy"
// d^2 = |q|^2 + |p|^2 - 2 q.p. LDS tile {px,py,pz,|p|^2}; registers hold -2q;
// |q|^2 added once after the min (monotone shift). Ref points processed in
// pairs so the min folds to v_min3_f32: 3.5 VALU/pair core loop.
template <int QPT, int CHUNK>
__global__ __launch_bounds__(256) void minsq_kernel(
    const float* __restrict__ tar, const float* __restrict__ src,
    unsigned int* __restrict__ ws, int N, int M)
{
    const int z   = blockIdx.z;
    const int dir = (z >= B_) ? 1 : 0;
    const int b   = dir ? (z - B_) : z;
    const float* __restrict__ qry = dir ? src : tar;
    const float* __restrict__ pts = dir ? tar : src;
    const int K = dir ? M : N;   // number of query points
    const int L = dir ? N : M;   // number of reference points
    unsigned int* __restrict__ out =
        ws + (dir ? (size_t)B_ * N : (size_t)0) + (size_t)b * K;

    const int base = blockIdx.y * CHUNK;
    if (base >= L) return;
    const int cnt = min(CHUNK, L - base);

    __shared__ float4 sp[CHUNK];
    const float* __restrict__ psrc = pts + ((size_t)b * L + base) * 3;
    const int t = threadIdx.x;
    for (int i = t; i < cnt; i += 256) {
        float px = psrc[3 * i + 0];
        float py = psrc[3 * i + 1];
        float pz = psrc[3 * i + 2];
        sp[i] = make_float4(px, py, pz, fmaf(px, px, fmaf(py, py, pz * pz)));
    }
    __syncthreads();

    const int qbase = blockIdx.x * (256 * QPT);
    float qx2[QPT], qy2[QPT], qz2[QPT], qw[QPT], mn[QPT];
#pragma unroll
    for (int k = 0; k < QPT; ++k) {
        int qi = qbase + k * 256 + t;
        if (qi < K) {
            const float* qp = qry + ((size_t)b * K + qi) * 3;
            float x = qp[0], y = qp[1], zc = qp[2];
            qx2[k] = -2.f * x; qy2[k] = -2.f * y; qz2[k] = -2.f * zc;
            qw[k] = fmaf(x, x, fmaf(y, y, zc * zc));
        } else {
            qx2[k] = 0.f; qy2[k] = 0.f; qz2[k] = 0.f; qw[k] = 0.f;
        }
        mn[k] = 3.4e38f;
    }

    if (cnt == CHUNK) {
#pragma unroll 4
        for (int j = 0; j < CHUNK; j += 2) {
            float4 p0 = sp[j];
            float4 p1 = sp[j + 1];
#pragma unroll
            for (int k = 0; k < QPT; ++k) {
                float d0 = fmaf(qx2[k], p0.x,
                           fmaf(qy2[k], p0.y,
                           fmaf(qz2[k], p0.z, p0.w)));
                float d1 = fmaf(qx2[k], p1.x,
                           fmaf(qy2[k], p1.y,
                           fmaf(qz2[k], p1.z, p1.w)));
                mn[k] = fminf(mn[k], fminf(d0, d1));   // -> v_min3_f32
            }
        }
    } else {
        int j = 0;
        for (; j + 1 < cnt; j += 2) {
            float4 p0 = sp[j];
            float4 p1 = sp[j + 1];
#pragma unroll
            for (int k = 0; k < QPT; ++k) {
                float d0 = fmaf(qx2[k], p0.x,
                           fmaf(qy2[k], p0.y,
                           fmaf(qz2[k], p0.z, p0.w)));
                float d1 = fmaf(qx2[k], p1.x,
                           fmaf(qy2[k], p1.y,
                           fmaf(qz2[k], p1.z, p1.w)));
                mn[k] = fminf(mn[k], fminf(d0, d1));
            }
        }
        if (j < cnt) {
            float4 p0 = sp[j];
#pragma unroll
            for (int k = 0; k < QPT; ++k) {
                float d0 = fmaf(qx2[k], p0.x,
                           fmaf(qy2[k], p0.y,
                           fmaf(qz2[k], p0.z, p0.w)));
                mn[k] = fminf(mn[k], d0);
            }
        }
    }

#pragma unroll
    for (int k = 0; k < QPT; ++k) {
        int qi = qbase + k * 256 + t;
        if (qi < K) {
            float d2 = fmaxf(mn[k] + qw[k], 0.f);   // clamp roundoff negatives
            atomicMin(&out[qi], __float_as_uint(d2));
        }
    }
}

// Stage 1: 128 blocks, each sums sqrt(min d^2) over a stripe of both regions,
// writes one partial per block per direction (no atomics, always written).
__global__ __launch_bounds__(256) void reduce1_kernel(
    const unsigned int* __restrict__ ws, float* __restrict__ partials,
    int N, int M)
{
    const int nt = B_ * N;
    const int ns = B_ * M;
    const int gid = blockIdx.x * 256 + threadIdx.x;
    const int stride = gridDim.x * 256;
    float s_t = 0.f, s_s = 0.f;
    for (int i = gid; i < nt; i += stride) s_t += sqrtf(__uint_as_float(ws[i]));
    for (int i = gid; i < ns; i += stride) s_s += sqrtf(__uint_as_float(ws[nt + i]));

#pragma unroll
    for (int off = 32; off > 0; off >>= 1) {
        s_t += __shfl_down(s_t, off);
        s_s += __shfl_down(s_s, off);
    }
    __shared__ float rt[4], rs[4];
    const int wid = threadIdx.x >> 6, lid = threadIdx.x & 63;
    if (lid == 0) { rt[wid] = s_t; rs[wid] = s_s; }
    __syncthreads();
    if (threadIdx.x == 0) {
        float a = rt[0] + rt[1] + rt[2] + rt[3];
        float c = rs[0] + rs[1] + rs[2] + rs[3];
        partials[blockIdx.x]       = a;
        partials[128 + blockIdx.x] = c;
    }
}

// Stage 2: one block sums the 128 partials per direction, writes outputs in
// reference order: (accuracy, complete, chamfer).
__global__ __launch_bounds__(128) void finalize_kernel(
    const float* __restrict__ partials, float* __restrict__ outp, int N, int M)
{
    const int t = threadIdx.x;   // 128 threads = 2 waves
    float s_t = partials[t];
    float s_s = partials[128 + t];
#pragma unroll
    for (int off = 32; off > 0; off >>= 1) {
        s_t += __shfl_down(s_t, off);
        s_s += __shfl_down(s_s, off);
    }
    __shared__ float rt[2], rs[2];
    if ((t & 63) == 0) { rt[t >> 6] = s_t; rs[t >> 6] = s_s; }
    __syncthreads();
    if (t == 0) {
        float complete = (rt[0] + rt[1]) / (float)(B_ * N);
        float accuracy = (rs[0] + rs[1]) / (float)(B_ * M);
        outp[0] = accuracy;
        outp[1] = complete;
        outp[2] = 0.5f * (accuracy + complete);
    }
}

extern "C" void kernel_launch(void* const* d_in, const int* in_sizes, int n_in,
                              void* d_out, int out_size, void* d_ws, size_t ws_size,
                              hipStream_t stream) {
    const float* tar = (const float*)d_in[0];
    const float* src = (const float*)d_in[1];
    const int N = in_sizes[0] / (B_ * 3);
    const int M = in_sizes[1] / (B_ * 3);
    unsigned int* ws = (unsigned int*)d_ws;
    float* partials = (float*)(ws + (size_t)B_ * (N + M));

    const int tot = B_ * (N + M);
    init_ws_kernel<<<dim3((tot + 255) / 256), dim3(256), 0, stream>>>(ws, tot);

    constexpr int QPT = 4, CHUNK = 512;
    const int KL = (N > M) ? N : M;
    const int gx = (KL + 256 * QPT - 1) / (256 * QPT);
    const int gy = (KL + CHUNK - 1) / CHUNK;
    dim3 grid(gx, gy, 2 * B_);
    minsq_kernel<QPT, CHUNK><<<grid, dim3(256), 0, stream>>>(tar, src, ws, N, M);

    reduce1_kernel<<<dim3(128), dim3(256), 0, stream>>>(ws, partials, N, M);
    finalize_kernel<<<dim3(1), dim3(128), 0, stream>>>(partials, (float*)d_out, N, M);
}